// Round 2
// baseline (7107.076 us; speedup 1.0000x reference)
//
#include <hip/hip_runtime.h>

// SocialModel LSTM scan, MI355X (gfx950).
//   256 "gate" blocks: (r = ped-group of 16) x (q = 8-hidden-unit slice) -> 32 gate cols each.
//     Wave map: 8 distinct cols x 8 ped-slots x 2 peds; XOR-swizzled LDS -> conflict-free GEMM reads.
//   64  "te"  blocks: 4 per grid cell; U_c resident in VGPRs; fp32 atomic message scatter.
//   2 grid barriers per step: atomic-counter arrive + direct poll + bounded-spin escape hatch.

#define TT    128
#define NPED  256
#define GC    16
#define CAP   256
#define NGATE 256
#define NTE   64
#define NB    (NGATE + NTE)

struct GateSmem {
    float4 W4[32][64];     // [col][k4 ^ (col&7)], K layout: h(128)|ie(64)|te(64) floats
    float4 hie[16][64];    // [ped][k4 ^ (ped&7)]: h slots 0..31 | ie 32..47 | te 48..63
    float  gates[16][33];  // +1 pad
    float  c_l[16][8];
    float  h_l[16][8];
    float  xl[16], yl[16];
    float  wout[5][8];
};
struct TeSmem {
    float4 hstage[128];    // h[j] for 4 pairs: [k] -> (p0,p1,p2,p3)
    float4 red[256];
};
union SmemU { GateSmem g; TeSmem t; };

__device__ __forceinline__ float sigf(float x) { return 1.0f / (1.0f + expf(-x)); }

#define DOT4(acc, w, a) acc = fmaf((w).x,(a).x, fmaf((w).y,(a).y, fmaf((w).z,(a).z, fmaf((w).w,(a).w,(acc)))))

// Monotonic atomic-counter grid barrier. cnt[0] = arrivals, cnt[1] = abort flag.
__device__ __forceinline__ void gbar(unsigned* cnt, unsigned target) {
    __syncthreads();
    if (threadIdx.x == 0) {
        __hip_atomic_fetch_add(cnt, 1u, __ATOMIC_ACQ_REL, __HIP_MEMORY_SCOPE_AGENT);
        int spin = 0;
        while (__hip_atomic_load(cnt, __ATOMIC_RELAXED, __HIP_MEMORY_SCOPE_AGENT) < target) {
            if (__hip_atomic_load(cnt + 1, __ATOMIC_RELAXED, __HIP_MEMORY_SCOPE_AGENT) != 0u) break;
            if (++spin > (1 << 20)) {  // escape hatch: deadlock -> fast wrong answer, not a hang
                __hip_atomic_store(cnt + 1, 1u, __ATOMIC_RELAXED, __HIP_MEMORY_SCOPE_AGENT);
                break;
            }
            __builtin_amdgcn_s_sleep(1);
        }
        __threadfence();   // acquire: pull all released data across XCD L2s
    }
    __syncthreads();
}

// ---------------- pair-list precompute (cell-grouped) ----------------
__global__ void __launch_bounds__(256)
social_pairs_kernel(const float* __restrict__ V, int* __restrict__ cnts, int* __restrict__ pairs)
{
    const float WB  = (float)(32.0/720.0*2.0), WBH = (float)(32.0/720.0);
    const float HB  = (float)(32.0/576.0*2.0), HBH = (float)(32.0/576.0);
    int t = blockIdx.x, i = threadIdx.x;
    __shared__ float xs[NPED], ys[NPED];
    xs[i] = V[t*NPED + i];
    ys[i] = V[TT*NPED + t*NPED + i];
    __syncthreads();
    float xi = xs[i], yi = ys[i];
    for (int j = 0; j < NPED; ++j) {
        if (j == i) continue;
        // replicate JAX fp32 op order: ((xj - xi) + wb/2) / wb * G, floor
        float cx = floorf((xs[j] - xi + WBH) / WB * 4.0f);
        float cy = floorf((ys[j] - yi + HBH) / HB * 4.0f);
        if (cx >= 0.0f && cx < 4.0f && cy >= 0.0f && cy < 4.0f) {
            int cell = (int)cx + 4 * (int)cy;
            int idx = atomicAdd(&cnts[t*GC + cell], 1);
            if (idx < CAP) pairs[(t*GC + cell)*CAP + idx] = (i << 16) | j;
        }
    }
}

// ---------------- persistent scan kernel ----------------
__global__ void __launch_bounds__(256, 2)
social_main_kernel(const float* __restrict__ V,
                   const float* __restrict__ W_emb, const float* __restrict__ b_emb,
                   const float* __restrict__ W_tens, const float* __restrict__ b_tens,
                   const float* __restrict__ W_ih, const float* __restrict__ b_ih,
                   const float* __restrict__ W_hh, const float* __restrict__ b_hh,
                   const float* __restrict__ W_out, const float* __restrict__ b_out,
                   float* __restrict__ h_buf,          // [2][256][128]
                   float* __restrict__ te_acc,         // [2][256][64]
                   const int* __restrict__ cnts, const int* __restrict__ pairs,
                   unsigned* __restrict__ bar,         // [2]: counter, abort
                   float* __restrict__ out)            // outs[128*256*5] | hT[256*128] | cT[256*128]
{
    __shared__ SmemU sm;
    const int tid = threadIdx.x;
    const int bid = blockIdx.x;
    unsigned gen = 0;

    if (bid < NGATE) {
        // ---------------- gate block ----------------
        const int r = bid >> 4, q = bid & 15;
        const int pedbase = r * 16;
        const int lane = tid & 63, wv = tid >> 6;
        const int slot = lane >> 3;               // ped slot 0..7 (peds slot, slot+8)
        const int hl   = lane & 7;
        const int lcol = wv*8 + hl;               // local col 0..31 ; lcol&7 == hl
        const int g4   = wv;                      // gate index i/f/g/o
        const int gc   = g4*128 + q*8 + hl;       // global gate column

        // one-time: stage swizzled weight slice. K: h(128)|ie(64)|te(64)
        for (int idx = tid; idx < 32*64; idx += 256) {
            int col = idx >> 6, k4 = idx & 63, k = k4*4;
            int cg4 = col >> 3, chl = col & 7;
            int cgc = cg4*128 + q*8 + chl;
            float4 w;
            if (k < 128)      w = *(const float4*)(W_hh + cgc*128 + k);
            else if (k < 192) w = *(const float4*)(W_ih + cgc*128 + (k - 128));
            else              w = *(const float4*)(W_ih + cgc*128 + 64 + (k - 192));
            sm.g.W4[col][k4 ^ chl] = w;
        }
        const float bias_c = b_ih[gc] + b_hh[gc];
        const int   e_  = tid & 63, p4_ = tid >> 6;        // ie mapping
        const float we0 = W_emb[e_*2], we1 = W_emb[e_*2+1], be = b_emb[e_];
        const int   e4_ = tid & 15, pte_ = tid >> 4;       // te-stage mapping
        const float4 bt4 = *(const float4*)(b_tens + e4_*4);
        const int   op_ = tid / 5, oo_ = tid - op_*5;      // outs mapping (tid<80)
        const float bo_ = (tid < 80) ? b_out[oo_] : 0.0f;
        if (tid < 40) { int o = tid >> 3, hh = tid & 7; sm.g.wout[o][hh] = W_out[o*128 + q*8 + hh]; }
        if (tid < 128) ((float*)sm.g.c_l)[tid] = 0.0f;
        __syncthreads();

        float acc0, acc1;
        for (int t = 0; t < TT; ++t) {
            const int cur = t & 1, nxt = cur ^ 1;
            const float* hb = h_buf + cur*NPED*128;
            // ---- phase A: stage h tile + positions, compute ie, K=192 GEMM ----
            {
                int pa = tid >> 5, ka = tid & 31;   // pa 0..7, ka 0..31
                sm.g.hie[pa][ka ^ (pa & 7)]     = *(const float4*)(hb + (pedbase+pa)*128 + ka*4);
                sm.g.hie[pa + 8][ka ^ (pa & 7)] = *(const float4*)(hb + (pedbase+pa+8)*128 + ka*4);
                if (tid < 16)      sm.g.xl[tid]    = V[t*NPED + pedbase + tid];
                else if (tid < 32) sm.g.yl[tid-16] = V[TT*NPED + t*NPED + pedbase + (tid-16)];
            }
            __syncthreads();
            {
                float* hf = (float*)sm.g.hie;
                #pragma unroll
                for (int j = 0; j < 4; ++j) {
                    int p = p4_*4 + j;
                    float v = fmaf(sm.g.yl[p], we1, fmaf(sm.g.xl[p], we0, be));
                    int j4 = (32 + (e_ >> 2)) ^ (p & 7);
                    hf[p*256 + j4*4 + (e_ & 3)] = fmaxf(v, 0.0f);
                }
            }
            __syncthreads();
            acc0 = 0.0f; acc1 = 0.0f;
            #pragma unroll 8
            for (int k4 = 0; k4 < 48; ++k4) {
                float4 w = sm.g.W4[lcol][k4 ^ hl];
                float4 a = sm.g.hie[slot][k4 ^ slot];
                float4 b = sm.g.hie[slot + 8][k4 ^ slot];
                DOT4(acc0, w, a);
                DOT4(acc1, w, b);
            }
            ++gen; gbar(bar, gen * NB);
            // ---- phase B: te K=64, pointwise LSTM, h/out writes ----
            {
                const float4* ta = (const float4*)(te_acc + cur*NPED*64);
                float4 v = ta[(pedbase + pte_)*16 + e4_];
                v.x = fmaxf(v.x + bt4.x, 0.f); v.y = fmaxf(v.y + bt4.y, 0.f);
                v.z = fmaxf(v.z + bt4.z, 0.f); v.w = fmaxf(v.w + bt4.w, 0.f);
                sm.g.hie[pte_][(48 + e4_) ^ (pte_ & 7)] = v;
            }
            __syncthreads();
            #pragma unroll
            for (int k4 = 48; k4 < 64; ++k4) {
                float4 w = sm.g.W4[lcol][k4 ^ hl];
                float4 a = sm.g.hie[slot][k4 ^ slot];
                float4 b = sm.g.hie[slot + 8][k4 ^ slot];
                DOT4(acc0, w, a);
                DOT4(acc1, w, b);
            }
            sm.g.gates[slot][lcol]     = acc0 + bias_c;
            sm.g.gates[slot + 8][lcol] = acc1 + bias_c;
            __syncthreads();
            if (tid < 128) {
                int p = tid >> 3, hh = tid & 7;
                float gi = sm.g.gates[p][hh];
                float gf = sm.g.gates[p][8  + hh];
                float gg = sm.g.gates[p][16 + hh];
                float go = sm.g.gates[p][24 + hh];
                float cold = sm.g.c_l[p][hh];
                float cn = sigf(gf)*cold + sigf(gi)*tanhf(gg);
                float hn = sigf(go)*tanhf(cn);
                sm.g.c_l[p][hh] = cn;
                sm.g.h_l[p][hh] = hn;
                h_buf[nxt*NPED*128 + (pedbase+p)*128 + q*8 + hh] = hn;
                if (t == TT-1) out[163840 + (pedbase+p)*128 + q*8 + hh] = hn;
            }
            __syncthreads();
            if (tid < 80) {  // partial out GEMM over this block's 8 hidden units
                float s = 0.0f;
                #pragma unroll
                for (int hh = 0; hh < 8; ++hh) s = fmaf(sm.g.h_l[op_][hh], sm.g.wout[oo_][hh], s);
                if (q == 0) s += bo_;
                unsafeAtomicAdd(&out[(t*NPED + pedbase + op_)*5 + oo_], s);
            }
            ++gen; gbar(bar, gen * NB);
        }
        // final cell state
        if (tid < 128) {
            int p = tid >> 3, hh = tid & 7;
            out[196608 + (pedbase+p)*128 + q*8 + hh] = sm.g.c_l[p][hh];
        }
    } else {
        // ---------------- te (social-tensor) block ----------------
        const int b = bid - NGATE;
        const int cell = b >> 2, slice = b & 3;
        const int e = tid & 63, qq = tid >> 6;
        float4 u[8];  // U_c[e][qq*32 .. +32) resident in VGPRs
        #pragma unroll
        for (int i4 = 0; i4 < 8; ++i4)
            u[i4] = *(const float4*)(W_tens + e*2048 + cell*128 + qq*32 + i4*4);

        for (int t = 0; t < TT; ++t) {
            const int cur = t & 1, nxt = cur ^ 1;
            const float* hb = h_buf + cur*NPED*128;
            float* ta = te_acc + cur*NPED*64;
            int cnt = cnts[t*GC + cell]; if (cnt > CAP) cnt = CAP;
            const int* pl = pairs + (t*GC + cell)*CAP;
            for (int g0 = slice*4; g0 < cnt; g0 += 16) {
                int lim = cnt - g0; if (lim > 4) lim = 4;
                int pv0 = (lim > 0) ? pl[g0+0] : 0;
                int pv1 = (lim > 1) ? pl[g0+1] : 0;
                int pv2 = (lim > 2) ? pl[g0+2] : 0;
                int pv3 = (lim > 3) ? pl[g0+3] : 0;
                int j0 = pv0 & 0xFFFF, j1 = pv1 & 0xFFFF, j2 = pv2 & 0xFFFF, j3 = pv3 & 0xFFFF;
                int i0 = pv0 >> 16,    i1 = pv1 >> 16,    i2 = pv2 >> 16,    i3 = pv3 >> 16;
                if (tid < 128) {
                    float4 hv;
                    hv.x = (lim > 0) ? hb[j0*128 + tid] : 0.0f;
                    hv.y = (lim > 1) ? hb[j1*128 + tid] : 0.0f;
                    hv.z = (lim > 2) ? hb[j2*128 + tid] : 0.0f;
                    hv.w = (lim > 3) ? hb[j3*128 + tid] : 0.0f;
                    sm.t.hstage[tid] = hv;
                }
                __syncthreads();
                float4 acc = make_float4(0.f, 0.f, 0.f, 0.f);
                #pragma unroll
                for (int i4 = 0; i4 < 8; ++i4) {
                    #pragma unroll
                    for (int s = 0; s < 4; ++s) {
                        float4 hv = sm.t.hstage[qq*32 + i4*4 + s];
                        float us = (s==0) ? u[i4].x : (s==1) ? u[i4].y : (s==2) ? u[i4].z : u[i4].w;
                        acc.x = fmaf(us, hv.x, acc.x);
                        acc.y = fmaf(us, hv.y, acc.y);
                        acc.z = fmaf(us, hv.z, acc.z);
                        acc.w = fmaf(us, hv.w, acc.w);
                    }
                }
                sm.t.red[tid] = acc;
                __syncthreads();
                if (tid < 64) {
                    float4 s0 = sm.t.red[e], s1 = sm.t.red[64+e], s2 = sm.t.red[128+e], s3 = sm.t.red[192+e];
                    float4 sum;
                    sum.x = s0.x+s1.x+s2.x+s3.x;
                    sum.y = s0.y+s1.y+s2.y+s3.y;
                    sum.z = s0.z+s1.z+s2.z+s3.z;
                    sum.w = s0.w+s1.w+s2.w+s3.w;
                    if (lim > 0) unsafeAtomicAdd(&ta[i0*64 + e], sum.x);
                    if (lim > 1) unsafeAtomicAdd(&ta[i1*64 + e], sum.y);
                    if (lim > 2) unsafeAtomicAdd(&ta[i2*64 + e], sum.z);
                    if (lim > 3) unsafeAtomicAdd(&ta[i3*64 + e], sum.w);
                }
                __syncthreads();
            }
            ++gen; gbar(bar, gen * NB);
            // zero the other te buffer for step t+1
            if (tid < 64)
                ((float4*)(te_acc + nxt*NPED*64))[b*64 + tid] = make_float4(0.f, 0.f, 0.f, 0.f);
            ++gen; gbar(bar, gen * NB);
        }
    }
}

extern "C" void kernel_launch(void* const* d_in, const int* in_sizes, int n_in,
                              void* d_out, int out_size, void* d_ws, size_t ws_size,
                              hipStream_t stream) {
    (void)in_sizes; (void)n_in; (void)ws_size;
    const float* V      = (const float*)d_in[0];
    // d_in[1] = PedsList (identity), unused
    const float* W_emb  = (const float*)d_in[2];
    const float* b_emb  = (const float*)d_in[3];
    const float* W_tens = (const float*)d_in[4];
    const float* b_tens = (const float*)d_in[5];
    const float* W_ih   = (const float*)d_in[6];
    const float* b_ih   = (const float*)d_in[7];
    const float* W_hh   = (const float*)d_in[8];
    const float* b_hh   = (const float*)d_in[9];
    const float* W_out  = (const float*)d_in[10];
    const float* b_out  = (const float*)d_in[11];

    // workspace layout (bytes), total 2500608 (needs ws_size >= ~2.5 MB):
    //   h_buf  [2][256][128] f32 @ 0        (262144)
    //   te_acc [2][256][64]  f32 @ 262144   (131072)
    //   cnts   [128][16]     i32 @ 393216   (8192)
    //   bar    [2]+pad       u32 @ 401408   (2048)
    //   pairs  [128][16][CAP]i32 @ 403456   (2097152)
    char* ws = (char*)d_ws;
    float*    h_buf  = (float*)(ws + 0);
    float*    te_acc = (float*)(ws + 262144);
    int*      cnts   = (int*)(ws + 393216);
    unsigned* bar    = (unsigned*)(ws + 401408);
    int*      pairs  = (int*)(ws + 403456);

    hipMemsetAsync(d_ws, 0, 403456, stream);                             // state + counters + barrier
    hipMemsetAsync(d_out, 0, (size_t)out_size * sizeof(float), stream);  // outs accumulated via atomics
    social_pairs_kernel<<<TT, 256, 0, stream>>>(V, cnts, pairs);
    social_main_kernel<<<NB, 256, 0, stream>>>(V, W_emb, b_emb, W_tens, b_tens,
                                               W_ih, b_ih, W_hh, b_hh, W_out, b_out,
                                               h_buf, te_acc, cnts, pairs, bar,
                                               (float*)d_out);
}

// Round 11
// 3567.207 us; speedup vs baseline: 1.9923x; 1.9923x over previous
//
#include <hip/hip_runtime.h>

// SocialModel LSTM scan, MI355X (gfx950).
//   256 "gate" blocks: (r = ped-group of 16) x (q = 8-hidden-unit slice) -> 32 gate cols each.
//     Wave map: 8 distinct cols x 8 ped-slots x 2 peds; XOR-swizzled LDS -> conflict-free GEMM reads.
//   64  "te"  blocks: 4 per grid cell, 16 waves/cell; U_cell rows resident in VGPRs (128/lane);
//     wave-synchronous pair loop (explicit lgkmcnt guard, no intra-block barriers), h prefetch.
//   Sync: per-block monotonic flags (release stores, relaxed polls) -- NO shared-counter RMWs.
//     gate(r,q) phase A waits gflag[r*16..+16) >= t  (own group's h(t))
//     te blocks       wait all 256 gflag >= t        (any h(t))
//     gate phase B    waits all 64 tflag >= t+1      (te(t) ready)
//   outs/hT computed by epilogue kernel from h history (no atomics on critical path).

#define TT    128
#define NPED  256
#define GC    16
#define CAP   256
#define NGATE 256
#define NTE   64
#define NB    (NGATE + NTE)
#define AGENT __HIP_MEMORY_SCOPE_AGENT

struct GateSmem {
    float4 W4[32][64];     // [col][k4 ^ (col&7)], K layout: h(128)|ie(64)|te(64) floats
    float4 hie[16][64];    // [ped][k4 ^ (ped&7)]: h slots 0..31 | ie 32..47 | te 48..63
    float  gates[16][33];  // +1 pad
    float  c_l[16][8];
    float  xl[16], yl[16];
};
struct TeSmem {
    float hst[4][128];     // per-wave h[j] staging
};
union SmemU { GateSmem g; TeSmem t; };

__device__ __forceinline__ float sigf(float x) { return 1.0f / (1.0f + expf(-x)); }
__device__ __forceinline__ unsigned ldf(const unsigned* p) {
    return __hip_atomic_load(p, __ATOMIC_RELAXED, AGENT);
}
// NOTE: was a macro; macro param `w` collided with the `.w` member token during
// preprocessing (`(a).w` -> `(a).<arg>`). An inline function has no such hazard.
__device__ __forceinline__ float dot4(float acc, float4 wv, float4 av) {
    return fmaf(wv.x, av.x, fmaf(wv.y, av.y, fmaf(wv.z, av.z, fmaf(wv.w, av.w, acc))));
}

// ---------------- pair-list precompute (cell-grouped) ----------------
__global__ void __launch_bounds__(256)
social_pairs_kernel(const float* __restrict__ V, int* __restrict__ cnts, int* __restrict__ pairs)
{
    const float WB  = (float)(32.0/720.0*2.0), WBH = (float)(32.0/720.0);
    const float HB  = (float)(32.0/576.0*2.0), HBH = (float)(32.0/576.0);
    int t = blockIdx.x, i = threadIdx.x;
    __shared__ float xs[NPED], ys[NPED];
    xs[i] = V[t*NPED + i];
    ys[i] = V[TT*NPED + t*NPED + i];
    __syncthreads();
    float xi = xs[i], yi = ys[i];
    for (int j = 0; j < NPED; ++j) {
        if (j == i) continue;
        // replicate JAX fp32 op order: ((xj - xi) + wb/2) / wb * G, floor
        float cx = floorf((xs[j] - xi + WBH) / WB * 4.0f);
        float cy = floorf((ys[j] - yi + HBH) / HB * 4.0f);
        if (cx >= 0.0f && cx < 4.0f && cy >= 0.0f && cy < 4.0f) {
            int cell = (int)cx + 4 * (int)cy;
            int idx = atomicAdd(&cnts[t*GC + cell], 1);
            if (idx < CAP) pairs[(t*GC + cell)*CAP + idx] = (i << 16) | j;
        }
    }
}

// ---------------- persistent scan kernel ----------------
__global__ void __launch_bounds__(256, 2)
social_main_kernel(const float* __restrict__ V,
                   const float* __restrict__ W_emb, const float* __restrict__ b_emb,
                   const float* __restrict__ W_tens, const float* __restrict__ b_tens,
                   const float* __restrict__ W_ih, const float* __restrict__ b_ih,
                   const float* __restrict__ W_hh, const float* __restrict__ b_hh,
                   float* __restrict__ h_hist,         // [TT+1][256][128]
                   float* __restrict__ te_acc,         // [2][256][64]
                   const int* __restrict__ cnts, const int* __restrict__ pairs,
                   unsigned* __restrict__ gflag,       // [256]
                   unsigned* __restrict__ tflag,       // [64]
                   unsigned* __restrict__ abw,         // abort word
                   float* __restrict__ out)            // cT written here at end
{
    __shared__ SmemU sm;
    const int tid  = threadIdx.x;
    const int bid  = blockIdx.x;
    const int lane = tid & 63, wv = tid >> 6;

    if (bid < NGATE) {
        // ---------------- gate block ----------------
        const int r = bid >> 4, q = bid & 15;
        const int pedbase = r * 16;
        const int slot = lane >> 3;               // ped slot 0..7 (peds slot, slot+8)
        const int hl   = lane & 7;
        const int lcol = wv*8 + hl;               // local col 0..31 ; lcol&7 == hl
        const int gc   = wv*128 + q*8 + hl;       // global gate column

        // one-time: stage swizzled weight slice. K: h(128)|ie(64)|te(64)
        for (int idx = tid; idx < 32*64; idx += 256) {
            int col = idx >> 6, k4 = idx & 63, k = k4*4;
            int cg4 = col >> 3, chl = col & 7;
            int cgc = cg4*128 + q*8 + chl;
            float4 w;
            if (k < 128)      w = *(const float4*)(W_hh + cgc*128 + k);
            else if (k < 192) w = *(const float4*)(W_ih + cgc*128 + (k - 128));
            else              w = *(const float4*)(W_ih + cgc*128 + 64 + (k - 192));
            sm.g.W4[col][k4 ^ chl] = w;
        }
        const float bias_c = b_ih[gc] + b_hh[gc];
        const int   e_  = tid & 63, p4_ = tid >> 6;        // ie mapping
        const float we0 = W_emb[e_*2], we1 = W_emb[e_*2+1], be = b_emb[e_];
        const int   e4_ = tid & 15, pte_ = tid >> 4;       // te-stage mapping
        const float4 bt4 = *(const float4*)(b_tens + e4_*4);
        if (tid < 128) ((float*)sm.g.c_l)[tid] = 0.0f;
        __syncthreads();

        for (int t = 0; t < TT; ++t) {
            const float* hb = h_hist + t*NPED*128;
            // ---- wait: own group's h(t) published ----
            if (wv == 0) {
                int spin = 0;
                for (;;) {
                    int ok = 1;
                    if (lane < 16) ok = (ldf(&gflag[(r<<4)+lane]) >= (unsigned)t) ? 1 : 0;
                    if (__all(ok)) break;
                    if (ldf(abw)) break;
                    if (++spin > (1<<18)) { __hip_atomic_store(abw, 1u, __ATOMIC_RELAXED, AGENT); break; }
                    __builtin_amdgcn_s_sleep(1);
                }
                __threadfence();
            }
            __syncthreads();
            // ---- phase A: stage h tile + positions, compute ie, K=192 GEMM ----
            {
                int pa = tid >> 5, ka = tid & 31;   // pa 0..7, ka 0..31
                sm.g.hie[pa][ka ^ (pa & 7)]     = *(const float4*)(hb + (pedbase+pa)*128 + ka*4);
                sm.g.hie[pa + 8][ka ^ (pa & 7)] = *(const float4*)(hb + (pedbase+pa+8)*128 + ka*4);
                if (tid < 16)      sm.g.xl[tid]    = V[t*NPED + pedbase + tid];
                else if (tid < 32) sm.g.yl[tid-16] = V[TT*NPED + t*NPED + pedbase + (tid-16)];
            }
            __syncthreads();
            {
                float* hf = (float*)sm.g.hie;
                #pragma unroll
                for (int j = 0; j < 4; ++j) {
                    int p = p4_*4 + j;
                    float v = fmaf(sm.g.yl[p], we1, fmaf(sm.g.xl[p], we0, be));
                    int j4 = (32 + (e_ >> 2)) ^ (p & 7);
                    hf[p*256 + j4*4 + (e_ & 3)] = fmaxf(v, 0.0f);
                }
            }
            __syncthreads();
            float acc0 = 0.0f, acc1 = 0.0f;
            #pragma unroll 8
            for (int k4 = 0; k4 < 48; ++k4) {
                float4 w = sm.g.W4[lcol][k4 ^ hl];
                float4 a = sm.g.hie[slot][k4 ^ slot];
                float4 b = sm.g.hie[slot + 8][k4 ^ slot];
                acc0 = dot4(acc0, w, a);
                acc1 = dot4(acc1, w, b);
            }
            // ---- wait: te(t) ready ----
            if (wv == 0) {
                int spin = 0;
                for (;;) {
                    int ok = (ldf(&tflag[lane]) >= (unsigned)(t+1)) ? 1 : 0;
                    if (__all(ok)) break;
                    if (ldf(abw)) break;
                    if (++spin > (1<<18)) { __hip_atomic_store(abw, 1u, __ATOMIC_RELAXED, AGENT); break; }
                    __builtin_amdgcn_s_sleep(1);
                }
                __threadfence();
            }
            __syncthreads();
            // ---- phase B: te K=64, pointwise LSTM, h write ----
            {
                const float4* ta = (const float4*)(te_acc + (t&1)*NPED*64);
                float4 v = ta[(pedbase + pte_)*16 + e4_];
                v.x = fmaxf(v.x + bt4.x, 0.f); v.y = fmaxf(v.y + bt4.y, 0.f);
                v.z = fmaxf(v.z + bt4.z, 0.f); v.w = fmaxf(v.w + bt4.w, 0.f);
                sm.g.hie[pte_][(48 + e4_) ^ (pte_ & 7)] = v;
            }
            __syncthreads();
            #pragma unroll
            for (int k4 = 48; k4 < 64; ++k4) {
                float4 w = sm.g.W4[lcol][k4 ^ hl];
                float4 a = sm.g.hie[slot][k4 ^ slot];
                float4 b = sm.g.hie[slot + 8][k4 ^ slot];
                acc0 = dot4(acc0, w, a);
                acc1 = dot4(acc1, w, b);
            }
            sm.g.gates[slot][lcol]     = acc0 + bias_c;
            sm.g.gates[slot + 8][lcol] = acc1 + bias_c;
            __syncthreads();
            if (tid < 128) {
                int p = tid >> 3, hh = tid & 7;
                float gi = sm.g.gates[p][hh];
                float gf = sm.g.gates[p][8  + hh];
                float gg = sm.g.gates[p][16 + hh];
                float go = sm.g.gates[p][24 + hh];
                float cold = sm.g.c_l[p][hh];
                float cn = sigf(gf)*cold + sigf(gi)*tanhf(gg);
                float hn = sigf(go)*tanhf(cn);
                sm.g.c_l[p][hh] = cn;
                h_hist[(t+1)*NPED*128 + (pedbase+p)*128 + q*8 + hh] = hn;
            }
            __syncthreads();
            if (tid == 0)
                __hip_atomic_store(&gflag[bid], (unsigned)(t+1), __ATOMIC_RELEASE, AGENT);
        }
        // final cell state
        if (tid < 128) {
            int p = tid >> 3, hh = tid & 7;
            out[196608 + (pedbase+p)*128 + q*8 + hh] = sm.g.c_l[p][hh];
        }
    } else {
        // ---------------- te (social-tensor) block ----------------
        const int b = bid - NGATE;
        const int cell = b >> 2;
        const int wloc = (b & 3)*4 + wv;      // wave index within cell: 0..15
        float4 u[32];                         // U_cell row `lane`: 128 floats in VGPRs
        #pragma unroll
        for (int i = 0; i < 32; ++i)
            u[i] = *(const float4*)(W_tens + lane*2048 + cell*128 + i*4);

        for (int t = 0; t < TT; ++t) {
            const float* hb = h_hist + t*NPED*128;
            // ---- wait: all h(t) published ----
            if (wv == 0) {
                int spin = 0;
                for (;;) {
                    int ok = 1;
                    #pragma unroll
                    for (int m = 0; m < 4; ++m)
                        ok &= (ldf(&gflag[lane*4 + m]) >= (unsigned)t) ? 1 : 0;
                    if (__all(ok)) break;
                    if (ldf(abw)) break;
                    if (++spin > (1<<18)) { __hip_atomic_store(abw, 1u, __ATOMIC_RELAXED, AGENT); break; }
                    __builtin_amdgcn_s_sleep(1);
                }
                __threadfence();
            }
            __syncthreads();
            // zero the other-parity buffer (used at t+1); safe: all gates passed their
            // reads of it (we saw gflag >= t, released after gates' phase B of t-1)
            if (tid < 64)
                ((float4*)(te_acc + ((t+1)&1)*NPED*64))[b*64 + tid] = make_float4(0.f,0.f,0.f,0.f);
            // ---- scatter messages (wave-synchronous, software-pipelined h loads) ----
            float* ta = te_acc + (t&1)*NPED*64;
            int cnt = cnts[t*GC + cell]; if (cnt > CAP) cnt = CAP;
            const int* pl = pairs + (t*GC + cell)*CAP;
            int idx = wloc;
            int    pv  = (idx < cnt) ? pl[idx] : 0;
            float2 hv  = (idx < cnt) ? ((const float2*)(hb + (pv & 0xFFFF)*128))[lane]
                                     : make_float2(0.f, 0.f);
            for (; idx < cnt; idx += 16) {
                // prefetch next pair's h while computing this one
                int    nidx = idx + 16;
                int    npv  = (nidx < cnt) ? pl[nidx] : 0;
                float2 nhv  = (nidx < cnt) ? ((const float2*)(hb + (npv & 0xFFFF)*128))[lane]
                                           : make_float2(0.f, 0.f);
                ((float2*)sm.t.hst[wv])[lane] = hv;
                // cross-lane LDS reuse within the wave: force write completion before
                // broadcast reads (do NOT rely on compiler alias analysis)
                asm volatile("s_waitcnt lgkmcnt(0)" ::: "memory");
                float acc = 0.0f;
                #pragma unroll
                for (int k4 = 0; k4 < 32; ++k4) {
                    float4 h4 = ((const float4*)sm.t.hst[wv])[k4];   // broadcast
                    acc = dot4(acc, u[k4], h4);
                }
                unsafeAtomicAdd(&ta[(pv >> 16)*64 + lane], acc);
                asm volatile("s_waitcnt lgkmcnt(0)" ::: "memory");   // reads done before next overwrite
                pv = npv; hv = nhv;
            }
            __syncthreads();
            if (tid == 0)
                __hip_atomic_store(&tflag[b], (unsigned)(t+1), __ATOMIC_RELEASE, AGENT);
        }
    }
}

// ---------------- epilogue: outs GEMM + hT copy ----------------
__global__ void __launch_bounds__(256)
social_out_kernel(const float* __restrict__ h_hist,
                  const float* __restrict__ W_out, const float* __restrict__ b_out,
                  float* __restrict__ out)
{
    __shared__ float w[5][128];
    __shared__ float bo[5];
    int t = blockIdx.x, tid = threadIdx.x;
    if (tid < 160) ((float4*)&w[0][0])[tid] = ((const float4*)W_out)[tid];
    if (tid < 5)   bo[tid] = b_out[tid];
    __syncthreads();
    if (t == TT) {
        // hT = h_hist[128]
        const float4* src = (const float4*)(h_hist + TT*NPED*128);
        float4* dst = (float4*)(out + 163840);
        for (int i = tid; i < 8192; i += 256) dst[i] = src[i];
    } else {
        const float4* hr = (const float4*)(h_hist + (t+1)*NPED*128 + tid*128);
        float a0 = bo[0], a1 = bo[1], a2 = bo[2], a3 = bo[3], a4 = bo[4];
        #pragma unroll 8
        for (int k4 = 0; k4 < 32; ++k4) {
            float4 hv = hr[k4];
            int k = k4*4;
            a0 += hv.x*w[0][k] + hv.y*w[0][k+1] + hv.z*w[0][k+2] + hv.w*w[0][k+3];
            a1 += hv.x*w[1][k] + hv.y*w[1][k+1] + hv.z*w[1][k+2] + hv.w*w[1][k+3];
            a2 += hv.x*w[2][k] + hv.y*w[2][k+1] + hv.z*w[2][k+2] + hv.w*w[2][k+3];
            a3 += hv.x*w[3][k] + hv.y*w[3][k+1] + hv.z*w[3][k+2] + hv.w*w[3][k+3];
            a4 += hv.x*w[4][k] + hv.y*w[4][k+1] + hv.z*w[4][k+2] + hv.w*w[4][k+3];
        }
        float* o = out + (t*NPED + tid)*5;
        o[0] = a0; o[1] = a1; o[2] = a2; o[3] = a3; o[4] = a4;
    }
}

extern "C" void kernel_launch(void* const* d_in, const int* in_sizes, int n_in,
                              void* d_out, int out_size, void* d_ws, size_t ws_size,
                              hipStream_t stream) {
    (void)in_sizes; (void)n_in; (void)ws_size; (void)out_size;
    const float* V      = (const float*)d_in[0];
    // d_in[1] = PedsList (identity), unused
    const float* W_emb  = (const float*)d_in[2];
    const float* b_emb  = (const float*)d_in[3];
    const float* W_tens = (const float*)d_in[4];
    const float* b_tens = (const float*)d_in[5];
    const float* W_ih   = (const float*)d_in[6];
    const float* b_ih   = (const float*)d_in[7];
    const float* W_hh   = (const float*)d_in[8];
    const float* b_hh   = (const float*)d_in[9];
    const float* W_out  = (const float*)d_in[10];
    const float* b_out  = (const float*)d_in[11];

    // workspace layout (bytes), total ~19.2 MB:
    //   h_hist [129][256][128] f32 @ 0         (16908288)
    //   te_acc [2][256][64]    f32 @ 16908288  (131072)
    //   cnts   [128][16]       i32 @ 17039360  (8192)
    //   gflag  [256]           u32 @ 17047552  (1024)
    //   tflag  [64]            u32 @ 17048576  (256)
    //   abort  [1]+pad         u32 @ 17048832  (256)
    //   pairs  [128][16][CAP]  i32 @ 17049088  (2097152)
    char* ws = (char*)d_ws;
    float*    h_hist = (float*)(ws + 0);
    float*    te_acc = (float*)(ws + 16908288);
    int*      cnts   = (int*)(ws + 17039360);
    unsigned* gflag  = (unsigned*)(ws + 17047552);
    unsigned* tflag  = (unsigned*)(ws + 17048576);
    unsigned* abw    = (unsigned*)(ws + 17048832);
    int*      pairs  = (int*)(ws + 17049088);

    (void)hipMemsetAsync(ws, 0, 131072, stream);               // h(0) = 0
    (void)hipMemsetAsync(ws + 16908288, 0, 140800, stream);    // te_acc + cnts + flags + abort
    social_pairs_kernel<<<TT, 256, 0, stream>>>(V, cnts, pairs);
    social_main_kernel<<<NB, 256, 0, stream>>>(V, W_emb, b_emb, W_tens, b_tens,
                                               W_ih, b_ih, W_hh, b_hh,
                                               h_hist, te_acc, cnts, pairs,
                                               gflag, tflag, abw, (float*)d_out);
    social_out_kernel<<<TT + 1, 256, 0, stream>>>(h_hist, W_out, b_out, (float*)d_out);
}